// Round 1
// 287.443 us; speedup vs baseline: 1.2640x; 1.2640x over previous
//
#include <hip/hip_runtime.h>
#include <hip/hip_bf16.h>

#define B_    32
#define SDEC  128
#define SENC  128
#define V_    32000
#define E_    200
#define H_    128
#define G3    384   // 3*H

typedef __attribute__((ext_vector_type(8))) short bf16x8;
typedef __attribute__((ext_vector_type(4))) float f32x4;

#define GLOBAL_AS __attribute__((address_space(1)))
#define LDS_AS    __attribute__((address_space(3)))

__device__ __forceinline__ float fast_sigmoid(float x) {
  return 1.f / (1.f + __expf(-x));
}
__device__ __forceinline__ float fast_tanh(float x) {
  // tanh(x) = 1 - 2/(exp(2x)+1); exact at both saturations.
  float e2 = __expf(2.f * x);
  return 1.f - 2.f / (e2 + 1.f);
}

// ---------------------------------------------------------------------------
// Kernel 1: x = emb[seq]; xg = x @ w_ih^T + b_ih   -> xg [4096][384] f32
// float4-vectorized LDS fill + inner product (E=200 = 50 float4 chunks).
// ---------------------------------------------------------------------------
__global__ __launch_bounds__(384) void k_embed_proj(
    const int* __restrict__ seq, const float* __restrict__ emb,
    const float* __restrict__ w_ih, const float* __restrict__ b_ih,
    float* __restrict__ xg) {
  __shared__ __align__(16) float xs[16][E_];
  __shared__ int sidx[16];
  const int r0 = blockIdx.x * 16;
  if (threadIdx.x < 16) sidx[threadIdx.x] = seq[r0 + threadIdx.x];
  __syncthreads();
  // 16 rows x 50 float4 = 800 vector loads
  for (int i = threadIdx.x; i < 800; i += 384) {
    int r = i / 50, c = i - r * 50;
    *(float4*)&xs[r][c * 4] =
        *(const float4*)(emb + (size_t)sidx[r] * E_ + c * 4);
  }
  __syncthreads();
  const int g = threadIdx.x;  // 0..383 gate output
  float acc[16];
#pragma unroll
  for (int r = 0; r < 16; r++) acc[r] = 0.f;
  const float* wg = w_ih + (size_t)g * E_;
  for (int k = 0; k < E_; k += 4) {
    float4 wv = *(const float4*)(wg + k);
#pragma unroll
    for (int r = 0; r < 16; r++) {
      float4 xv = *(const float4*)&xs[r][k];
      acc[r] += wv.x * xv.x + wv.y * xv.y + wv.z * xv.z + wv.w * xv.w;
    }
  }
  const float bb = b_ih[g];
#pragma unroll
  for (int r = 0; r < 16; r++) xg[(size_t)(r0 + r) * G3 + g] = acc[r] + bb;
}

// ---------------------------------------------------------------------------
// Kernel 2: fused GRU scan (blocks 0..31, one per batch, 512 thr)
//           + w_out f32->bf16 convert (blocks 32..2031) to fill idle CUs.
// GRU: register-prefetched xg (hides ~500cy L2/L3 latency under the matvec),
// ds_read_b128 hprev loads, exp2-based activations.
// ---------------------------------------------------------------------------
__global__ __launch_bounds__(512) void k_gru_cvt(
    const float* __restrict__ xg, const float* __restrict__ h0,
    const float* __restrict__ w_hh, const float* __restrict__ b_hh,
    float* __restrict__ cat, __hip_bfloat16* __restrict__ cat_bf,
    float* __restrict__ state_out,
    const float* __restrict__ w_out, __hip_bfloat16* __restrict__ wout_bf) {
  if (blockIdx.x >= 32) {
    // ---- cvt part: 2000 blocks x 512 thr x 8 elems = 32000*256 ----
    int idx = ((blockIdx.x - 32) * 512 + threadIdx.x) * 8;
    float4 a = *(const float4*)(w_out + idx);
    float4 c = *(const float4*)(w_out + idx + 4);
    union { __hip_bfloat16 h[8]; uint4 v; } p;
    p.h[0] = __float2bfloat16(a.x); p.h[1] = __float2bfloat16(a.y);
    p.h[2] = __float2bfloat16(a.z); p.h[3] = __float2bfloat16(a.w);
    p.h[4] = __float2bfloat16(c.x); p.h[5] = __float2bfloat16(c.y);
    p.h[6] = __float2bfloat16(c.z); p.h[7] = __float2bfloat16(c.w);
    *(uint4*)(wout_bf + idx) = p.v;
    return;
  }

  const int b = blockIdx.x;
  const int t = threadIdx.x;
  const int hh = t & 127;
  const int q = t >> 7;  // 0..3 K-quarter

  float wr_[32], wz_[32], wn_[32];
#pragma unroll
  for (int j4 = 0; j4 < 8; j4++) {
    *(float4*)&wr_[j4 * 4] =
        *(const float4*)(w_hh + (size_t)hh * H_ + q * 32 + j4 * 4);
    *(float4*)&wz_[j4 * 4] =
        *(const float4*)(w_hh + (size_t)(128 + hh) * H_ + q * 32 + j4 * 4);
    *(float4*)&wn_[j4 * 4] =
        *(const float4*)(w_hh + (size_t)(256 + hh) * H_ + q * 32 + j4 * 4);
  }

  __shared__ __align__(16) float hprev[H_];
  __shared__ float part[3][4][H_];
  float br = 0.f, bz = 0.f, bn = 0.f;
  float cxr = 0.f, cxz = 0.f, cxn = 0.f;
  const float* xgb = xg + (size_t)b * SDEC * G3;
  if (t < H_) {
    hprev[t] = h0[b * H_ + t];
    br = b_hh[hh]; bz = b_hh[128 + hh]; bn = b_hh[256 + hh];
    cxr = xgb[hh]; cxz = xgb[128 + hh]; cxn = xgb[256 + hh];
  }
  float* catb = cat + (size_t)b * SDEC * 256;
  __hip_bfloat16* catbfb = cat_bf + (size_t)b * SDEC * 256;
  __syncthreads();

  for (int s = 0; s < SDEC; s++) {
    // prefetch next step's input gates early; consumed only at loop bottom
    float nxr = 0.f, nxz = 0.f, nxn = 0.f;
    if (t < H_ && s + 1 < SDEC) {
      const float* xp = xgb + (size_t)(s + 1) * G3;
      nxr = xp[hh]; nxz = xp[128 + hh]; nxn = xp[256 + hh];
    }
    float sr = 0.f, sz = 0.f, sn = 0.f;
#pragma unroll
    for (int j4 = 0; j4 < 8; j4++) {
      float4 hv = *(const float4*)&hprev[q * 32 + j4 * 4];
      sr += wr_[j4 * 4 + 0] * hv.x + wr_[j4 * 4 + 1] * hv.y +
            wr_[j4 * 4 + 2] * hv.z + wr_[j4 * 4 + 3] * hv.w;
      sz += wz_[j4 * 4 + 0] * hv.x + wz_[j4 * 4 + 1] * hv.y +
            wz_[j4 * 4 + 2] * hv.z + wz_[j4 * 4 + 3] * hv.w;
      sn += wn_[j4 * 4 + 0] * hv.x + wn_[j4 * 4 + 1] * hv.y +
            wn_[j4 * 4 + 2] * hv.z + wn_[j4 * 4 + 3] * hv.w;
    }
    part[0][q][hh] = sr;
    part[1][q][hh] = sz;
    part[2][q][hh] = sn;
    __syncthreads();
    if (t < H_) {
      float hr = part[0][0][hh] + part[0][1][hh] + part[0][2][hh] + part[0][3][hh] + br;
      float hz = part[1][0][hh] + part[1][1][hh] + part[1][2][hh] + part[1][3][hh] + bz;
      float hn = part[2][0][hh] + part[2][1][hh] + part[2][2][hh] + part[2][3][hh] + bn;
      float r = fast_sigmoid(cxr + hr);
      float z = fast_sigmoid(cxz + hz);
      float n = fast_tanh(cxn + r * hn);
      float hnew = (1.f - z) * n + z * hprev[hh];
      hprev[hh] = hnew;
      catb[(size_t)s * 256 + hh] = hnew;
      catbfb[(size_t)s * 256 + hh] = __float2bfloat16(hnew);
    }
    __syncthreads();
    cxr = nxr; cxz = nxz; cxn = nxn;
  }
  if (t < H_) state_out[b * H_ + t] = hprev[t];
}

// ---------------------------------------------------------------------------
// Kernel 3: attention. TWO blocks per batch (d-half split), 256 threads.
// cat rows staged into LDS (was: global reads inside the k-loop).
// ---------------------------------------------------------------------------
__global__ __launch_bounds__(256) void k_attn(
    const float* __restrict__ hs, const float* __restrict__ cat,
    float* __restrict__ attw_out, __hip_bfloat16* __restrict__ cat_bf) {
  __shared__ float hsb[SENC][H_ + 1];   // 66.0 KB
  __shared__ float ctb[64][H_ + 1];     // 33.0 KB
  __shared__ float sbuf[SENC][64 + 1];  // 33.3 KB  (total 132.3 KB)
  const int b = blockIdx.x >> 1;
  const int d0 = (blockIdx.x & 1) * 64;
  const int t = threadIdx.x;
  const float* hsbase = hs + (size_t)b * SENC * H_;

  // phase 1: stage hs (128x128) and this half's cat rows (64x128)
  for (int i = t; i < 4096; i += 256) {  // float4 granules of hs
    int r = i >> 5, c = (i & 31) * 4;
    float4 v = *(const float4*)(hsbase + r * H_ + c);
    hsb[r][c] = v.x; hsb[r][c + 1] = v.y; hsb[r][c + 2] = v.z; hsb[r][c + 3] = v.w;
  }
  for (int i = t; i < 2048; i += 256) {  // float4 granules of cat half
    int r = i >> 5, c = (i & 31) * 4;
    float4 v = *(const float4*)(cat + (size_t)(b * SDEC + d0 + r) * 256 + c);
    ctb[r][c] = v.x; ctb[r][c + 1] = v.y; ctb[r][c + 2] = v.z; ctb[r][c + 3] = v.w;
  }
  __syncthreads();

  // phase 2: scores s[e][d], e-tile 8 (te=t>>4), d-tile 4 (td=t&15)
  {
    const int te = t >> 4, td = t & 15;
    float acc[8][4];
#pragma unroll
    for (int i = 0; i < 8; i++)
#pragma unroll
      for (int j = 0; j < 4; j++) acc[i][j] = 0.f;
#pragma unroll 2
    for (int k = 0; k < H_; k++) {
      float av[8], bv[4];
#pragma unroll
      for (int i = 0; i < 8; i++) av[i] = hsb[te * 8 + i][k];
#pragma unroll
      for (int j = 0; j < 4; j++) bv[j] = ctb[td * 4 + j][k];
#pragma unroll
      for (int i = 0; i < 8; i++)
#pragma unroll
        for (int j = 0; j < 4; j++) acc[i][j] += av[i] * bv[j];
    }
#pragma unroll
    for (int i = 0; i < 8; i++)
#pragma unroll
      for (int j = 0; j < 4; j++) sbuf[te * 8 + i][td * 4 + j] = acc[i][j];
  }
  __syncthreads();

  // phase 3: softmax over e for each of this half's 64 columns
  if (t < 64) {
    const int d = t;
    float m = -1e30f;
    for (int e = 0; e < SENC; e++) m = fmaxf(m, sbuf[e][d]);
    float sum = 0.f;
    for (int e = 0; e < SENC; e++) {
      float p = __expf(sbuf[e][d] - m);
      sbuf[e][d] = p;
      sum += p;
    }
    float inv = 1.f / sum;
    for (int e = 0; e < SENC; e++) {
      float p = sbuf[e][d] * inv;
      sbuf[e][d] = p;
      attw_out[(size_t)b * SENC * SDEC + (size_t)e * SDEC + d0 + d] = p;
    }
  }
  __syncthreads();

  // phase 4: context c[d][h] -> cat_bf[:,128:256]
  // d-tile 4 (td=t>>4 in 0..15), h strided th+16*j (conflict-free hsb reads)
  {
    const int td = t >> 4, th = t & 15;
    float acc[4][8];
#pragma unroll
    for (int i = 0; i < 4; i++)
#pragma unroll
      for (int j = 0; j < 8; j++) acc[i][j] = 0.f;
#pragma unroll 2
    for (int e = 0; e < SENC; e++) {
      float pv[4], hv[8];
#pragma unroll
      for (int i = 0; i < 4; i++) pv[i] = sbuf[e][td * 4 + i];
#pragma unroll
      for (int j = 0; j < 8; j++) hv[j] = hsb[e][th + 16 * j];
#pragma unroll
      for (int i = 0; i < 4; i++)
#pragma unroll
        for (int j = 0; j < 8; j++) acc[i][j] += pv[i] * hv[j];
    }
#pragma unroll
    for (int i = 0; i < 4; i++)
#pragma unroll
      for (int j = 0; j < 8; j++)
        cat_bf[(size_t)(b * SDEC + d0 + td * 4 + i) * 256 + 128 + th + 16 * j] =
            __float2bfloat16(acc[i][j]);
  }
}

// ---------------------------------------------------------------------------
// Kernel 4: logits = cat @ w_out^T + b_out   (unchanged — near write-BW floor)
// 128m x 256n tile, 512 thr (8 waves 2Mx4N), Kt=32 -> 8 K-steps.
// 3-buffer, 2-deep counted vmcnt(3); LDS-transpose epilogue.
// ---------------------------------------------------------------------------
__global__ __launch_bounds__(512) void k_gemm_mfma(
    const __hip_bfloat16* __restrict__ A, const __hip_bfloat16* __restrict__ Bw,
    const float* __restrict__ b_out, float* __restrict__ C) {
  constexpr int K = 256, N = V_, Kt = 32;
  alignas(16) __shared__ char smem[73728];  // 72 KB
  __hip_bfloat16 (*As)[4096] = (__hip_bfloat16(*)[4096])smem;            // [3][128*32]
  __hip_bfloat16 (*Bs)[8192] = (__hip_bfloat16(*)[8192])(smem + 24576);  // [3][256*32]
  float* tr = (float*)smem;  // epilogue: [64][260] padded f32 half-tile

  const int tid = threadIdx.x;
  const int w = tid >> 6, l = tid & 63;
  const int wr = w >> 2, wc = w & 3;       // 2M x 4N waves, each 64x64
  const int lr = l & 15, lk = l >> 4;
  const int lq = l >> 2, lc = l & 3;       // staging: lane -> (row-in-16, 16B chunk)

  // bijective XCD swizzle: 4000 = 8 x 500; m fastest within an XCD chunk
  const int bid = blockIdx.x;
  const int wgid = (bid & 7) * 500 + (bid >> 3);
  const int mt = wgid & 31;    // 0..31
  const int nt = wgid >> 5;    // 0..124
  const int m0 = mt * 128, n0 = nt * 256;

  f32x4 acc[4][4];
#pragma unroll
  for (int m = 0; m < 4; m++)
#pragma unroll
    for (int n = 0; n < 4; n++) acc[m][n] = (f32x4){0.f, 0.f, 0.f, 0.f};

#define STAGE(buf, kk)                                                            \
  do {                                                                            \
    const __hip_bfloat16* gA = A + (size_t)(m0 + w * 16 + lq) * K + (kk) + lc * 8;\
    const __hip_bfloat16* gB0 = Bw + (size_t)(n0 + w * 32 + lq) * K + (kk) + lc * 8;\
    const __hip_bfloat16* gB1 = gB0 + (size_t)16 * K;                             \
    __builtin_amdgcn_global_load_lds((const GLOBAL_AS void*)gA,                   \
        (LDS_AS void*)(&As[buf][w * 512]), 16, 0, 0);                             \
    __builtin_amdgcn_global_load_lds((const GLOBAL_AS void*)gB0,                  \
        (LDS_AS void*)(&Bs[buf][w * 1024]), 16, 0, 0);                            \
    __builtin_amdgcn_global_load_lds((const GLOBAL_AS void*)gB1,                  \
        (LDS_AS void*)(&Bs[buf][w * 1024 + 512]), 16, 0, 0);                      \
  } while (0)

  STAGE(0, 0);
  STAGE(1, Kt);

#pragma unroll
  for (int t = 0; t < 8; ++t) {
    if (t < 7) asm volatile("s_waitcnt vmcnt(3)" ::: "memory");  // tile t landed
    else       asm volatile("s_waitcnt vmcnt(0)" ::: "memory");
    __builtin_amdgcn_s_barrier();
    asm volatile("" ::: "memory");

    const int c = t % 3;
    bf16x8 af[4], bfr[4];
#pragma unroll
    for (int m = 0; m < 4; m++)
      af[m] = *(const bf16x8*)(const void*)(&As[c][(wr * 64 + m * 16 + lr) * Kt + lk * 8]);
#pragma unroll
    for (int n = 0; n < 4; n++)
      bfr[n] = *(const bf16x8*)(const void*)(&Bs[c][(wc * 64 + n * 16 + lr) * Kt + lk * 8]);

    if (t < 6) STAGE((t + 2) % 3, (t + 2) * Kt);

    // swapped operands: lane (lr,lk) holds C[m*16+lr][n*16+lk*4 + j], j=0..3
#pragma unroll
    for (int m = 0; m < 4; m++)
#pragma unroll
      for (int n = 0; n < 4; n++)
        acc[m][n] = __builtin_amdgcn_mfma_f32_16x16x32_bf16(bfr[n], af[m], acc[m][n], 0, 0, 0);
  }
#undef STAGE

  // ------------- epilogue: LDS transpose -> 1KB-run coalesced nt stores -----
  __syncthreads();  // staging LDS reads fully drained before reuse
#pragma unroll
  for (int h = 0; h < 2; ++h) {
    if (wr == h) {
#pragma unroll
      for (int m = 0; m < 4; m++) {
#pragma unroll
        for (int n = 0; n < 4; n++) {
          const int row = m * 16 + lr;                 // 0..63 within half
          const int col = wc * 64 + n * 16 + lk * 4;   // 0..255
          const float4 bo = *(const float4*)(b_out + n0 + col);
          f32x4 v;
          v[0] = acc[m][n][0] + bo.x;
          v[1] = acc[m][n][1] + bo.y;
          v[2] = acc[m][n][2] + bo.z;
          v[3] = acc[m][n][3] + bo.w;
          *(f32x4*)&tr[row * 260 + col] = v;
        }
      }
    }
    __syncthreads();
#pragma unroll
    for (int i = 0; i < 8; ++i) {
      const int c2 = i * 512 + tid;      // 0..4095
      const int row = c2 >> 6;           // 0..63
      const int off = (c2 & 63) * 4;     // 0..252 floats
      f32x4 v = *(const f32x4*)&tr[row * 260 + off];
      __builtin_nontemporal_store(
          v, (f32x4*)(C + (size_t)(m0 + h * 64 + row) * N + n0 + off));
    }
    __syncthreads();
  }
}

// ---------------------------------------------------------------------------
extern "C" void kernel_launch(void* const* d_in, const int* in_sizes, int n_in,
                              void* d_out, int out_size, void* d_ws, size_t ws_size,
                              hipStream_t stream) {
  const int* seq = (const int*)d_in[0];
  const float* hs = (const float*)d_in[1];
  const float* h0 = (const float*)d_in[2];
  const float* emb = (const float*)d_in[3];
  const float* w_ih = (const float*)d_in[4];
  const float* w_hh = (const float*)d_in[5];
  const float* b_ih = (const float*)d_in[6];
  const float* b_hh = (const float*)d_in[7];
  const float* w_out = (const float*)d_in[8];
  const float* b_out = (const float*)d_in[9];

  float* out = (float*)d_out;
  float* logits = out;                          // 131,072,000 f32
  float* state = out + 131072000;               // 4,096 f32
  float* attw = out + 131072000 + 4096;         // 524,288 f32

  char* ws = (char*)d_ws;
  float* xg = (float*)ws;                              // 6,291,456 B
  float* cat = (float*)(ws + 6291456);                 // 4,194,304 B  [4096][256] f32
  __hip_bfloat16* cat_bf = (__hip_bfloat16*)(ws + 10485760);   // 2,097,152 B
  __hip_bfloat16* wout_bf = (__hip_bfloat16*)(ws + 12582912);  // 16,384,000 B

  k_embed_proj<<<256, 384, 0, stream>>>(seq, emb, w_ih, b_ih, xg);
  k_gru_cvt<<<2032, 512, 0, stream>>>(xg, h0, w_hh, b_hh, cat, cat_bf, state,
                                      w_out, wout_bf);
  k_attn<<<64, 256, 0, stream>>>(hs, cat, attw, cat_bf);
  k_gemm_mfma<<<4000, 512, 0, stream>>>(cat_bf, wout_bf, b_out, logits);
}

// Round 2
// 273.368 us; speedup vs baseline: 1.3291x; 1.0515x over previous
//
#include <hip/hip_runtime.h>
#include <hip/hip_bf16.h>

#define B_    32
#define SDEC  128
#define SENC  128
#define V_    32000
#define E_    200
#define H_    128
#define G3    384   // 3*H

typedef __attribute__((ext_vector_type(8))) short bf16x8;
typedef __attribute__((ext_vector_type(4))) float f32x4;

#define GLOBAL_AS __attribute__((address_space(1)))
#define LDS_AS    __attribute__((address_space(3)))

__device__ __forceinline__ float fast_sigmoid(float x) {
  return 1.f / (1.f + __expf(-x));
}
__device__ __forceinline__ float fast_tanh(float x) {
  float e2 = __expf(2.f * x);
  return 1.f - 2.f / (e2 + 1.f);
}

// ---------------------------------------------------------------------------
// Kernel 1: x = emb[seq]; xg = x @ w_ih^T + b_ih   -> xg [4096][384] f32
// 192 threads, 2 gate-columns per thread: halves LDS broadcast-read instrs.
// ---------------------------------------------------------------------------
__global__ __launch_bounds__(192) void k_embed_proj(
    const int* __restrict__ seq, const float* __restrict__ emb,
    const float* __restrict__ w_ih, const float* __restrict__ b_ih,
    float* __restrict__ xg) {
  __shared__ __align__(16) float xs[16][E_];
  __shared__ int sidx[16];
  const int r0 = blockIdx.x * 16;
  const int t = threadIdx.x;
  if (t < 16) sidx[t] = seq[r0 + t];
  __syncthreads();
  for (int i = t; i < 800; i += 192) {
    int r = i / 50, c = i - r * 50;
    *(float4*)&xs[r][c * 4] =
        *(const float4*)(emb + (size_t)sidx[r] * E_ + c * 4);
  }
  __syncthreads();
  const int g0 = t, g1 = t + 192;
  float a0[16], a1[16];
#pragma unroll
  for (int r = 0; r < 16; r++) { a0[r] = 0.f; a1[r] = 0.f; }
  const float* w0 = w_ih + (size_t)g0 * E_;
  const float* w1 = w_ih + (size_t)g1 * E_;
  for (int k = 0; k < E_; k += 4) {
    float4 wv0 = *(const float4*)(w0 + k);
    float4 wv1 = *(const float4*)(w1 + k);
#pragma unroll
    for (int r = 0; r < 16; r++) {
      float4 xv = *(const float4*)&xs[r][k];
      a0[r] += wv0.x * xv.x + wv0.y * xv.y + wv0.z * xv.z + wv0.w * xv.w;
      a1[r] += wv1.x * xv.x + wv1.y * xv.y + wv1.z * xv.z + wv1.w * xv.w;
    }
  }
  const float b0 = b_ih[g0], b1 = b_ih[g1];
#pragma unroll
  for (int r = 0; r < 16; r++) {
    xg[(size_t)(r0 + r) * G3 + g0] = a0[r] + b0;
    xg[(size_t)(r0 + r) * G3 + g1] = a1[r] + b1;
  }
}

// ---------------------------------------------------------------------------
// Kernel 2: fused GRU scan (blocks 0..31) + w_out f32->bf16 (blocks 32..2031).
// GRU remap: thread t -> (hh = t>>2, sub = t&3). Each 4-lane group owns one
// h element; k-quarter reduction via __shfl_xor (no barrier, no LDS part[]).
// All 4 lanes compute activations redundantly (no divergence). Double-buffered
// hprev -> ONE barrier per step. Rotated broadcast reads (conflict-free).
// ---------------------------------------------------------------------------
__global__ __launch_bounds__(512) void k_gru_cvt(
    const float* __restrict__ xg, const float* __restrict__ h0,
    const float* __restrict__ w_hh, const float* __restrict__ b_hh,
    float* __restrict__ cat, __hip_bfloat16* __restrict__ cat_bf,
    float* __restrict__ state_out,
    const float* __restrict__ w_out, __hip_bfloat16* __restrict__ wout_bf) {
  if (blockIdx.x >= 32) {
    int idx = ((blockIdx.x - 32) * 512 + threadIdx.x) * 8;
    float4 a = *(const float4*)(w_out + idx);
    float4 c = *(const float4*)(w_out + idx + 4);
    union { __hip_bfloat16 h[8]; uint4 v; } p;
    p.h[0] = __float2bfloat16(a.x); p.h[1] = __float2bfloat16(a.y);
    p.h[2] = __float2bfloat16(a.z); p.h[3] = __float2bfloat16(a.w);
    p.h[4] = __float2bfloat16(c.x); p.h[5] = __float2bfloat16(c.y);
    p.h[6] = __float2bfloat16(c.z); p.h[7] = __float2bfloat16(c.w);
    *(uint4*)(wout_bf + idx) = p.v;
    return;
  }

  const int b = blockIdx.x;
  const int t = threadIdx.x;
  const int hh = t >> 2;   // 0..127: owned h element
  const int sub = t & 3;   // k-quarter

  // weights stored in rotated chunk order (matches rotated hprev reads)
  float wr_[32], wz_[32], wn_[32];
#pragma unroll
  for (int m = 0; m < 8; m++) {
    int c = (m + sub * 2) & 7;
    int kb = sub * 32 + c * 4;
    *(float4*)&wr_[m * 4] = *(const float4*)(w_hh + (size_t)hh * H_ + kb);
    *(float4*)&wz_[m * 4] = *(const float4*)(w_hh + (size_t)(128 + hh) * H_ + kb);
    *(float4*)&wn_[m * 4] = *(const float4*)(w_hh + (size_t)(256 + hh) * H_ + kb);
  }

  __shared__ __align__(16) float hp[2][H_];
  const float* xgb = xg + (size_t)b * SDEC * G3;
  const float br = b_hh[hh], bz = b_hh[128 + hh], bn = b_hh[256 + hh];
  float cxr = xgb[hh], cxz = xgb[128 + hh], cxn = xgb[256 + hh];
  if (t < H_) hp[0][t] = h0[b * H_ + t];
  float* catb = cat + (size_t)b * SDEC * 256;
  __hip_bfloat16* catbfb = cat_bf + (size_t)b * SDEC * 256;
  __syncthreads();

  int cur = 0;
  for (int s = 0; s < SDEC; s++) {
    float nxr = 0.f, nxz = 0.f, nxn = 0.f;
    if (s + 1 < SDEC) {
      const float* xp = xgb + (size_t)(s + 1) * G3;
      nxr = xp[hh]; nxz = xp[128 + hh]; nxn = xp[256 + hh];
    }
    float sr = 0.f, sz = 0.f, sn = 0.f;
#pragma unroll
    for (int m = 0; m < 8; m++) {
      int c = (m + sub * 2) & 7;
      float4 hv = *(const float4*)&hp[cur][sub * 32 + c * 4];
      sr += wr_[m * 4 + 0] * hv.x + wr_[m * 4 + 1] * hv.y +
            wr_[m * 4 + 2] * hv.z + wr_[m * 4 + 3] * hv.w;
      sz += wz_[m * 4 + 0] * hv.x + wz_[m * 4 + 1] * hv.y +
            wz_[m * 4 + 2] * hv.z + wz_[m * 4 + 3] * hv.w;
      sn += wn_[m * 4 + 0] * hv.x + wn_[m * 4 + 1] * hv.y +
            wn_[m * 4 + 2] * hv.z + wn_[m * 4 + 3] * hv.w;
    }
    // reduce the 4 k-quarters within each 4-lane group (no barrier)
    sr += __shfl_xor(sr, 1); sr += __shfl_xor(sr, 2);
    sz += __shfl_xor(sz, 1); sz += __shfl_xor(sz, 2);
    sn += __shfl_xor(sn, 1); sn += __shfl_xor(sn, 2);

    float hold = hp[cur][hh];
    float r = fast_sigmoid(cxr + sr + br);
    float z = fast_sigmoid(cxz + sz + bz);
    float n = fast_tanh(cxn + r * (sn + bn));
    float hnew = (1.f - z) * n + z * hold;
    if (sub == 0) {
      hp[cur ^ 1][hh] = hnew;
      catb[(size_t)s * 256 + hh] = hnew;
      catbfb[(size_t)s * 256 + hh] = __float2bfloat16(hnew);
    }
    __syncthreads();
    cur ^= 1;
    cxr = nxr; cxz = nxz; cxn = nxn;
  }
  if (t < H_) state_out[b * H_ + t] = hp[cur][t];
}

// ---------------------------------------------------------------------------
// Kernel 3: attention. 2 blocks/batch (d-half), 256 threads.
// All LDS traffic as b128 with XOR chunk-swizzles (16B row strides make any
// 8-row spread bank-identical; swizzle restores spread). sbuf transposed to
// [d][e] so softmax + phase-4 P reads are row-contiguous float4.
// ---------------------------------------------------------------------------
__global__ __launch_bounds__(256) void k_attn(
    const float* __restrict__ hs, const float* __restrict__ cat,
    float* __restrict__ attw_out, __hip_bfloat16* __restrict__ cat_bf) {
  __shared__ __align__(16) float hsb[SENC][H_];   // 64 KB, chunk ^ ((r>>3)&3)
  __shared__ __align__(16) float ctb[64][H_];     // 32 KB, chunk ^ ((r>>2)&7)
  __shared__ __align__(16) float sbuf[64][SENC];  // 32 KB, [d][e], chunk ^ ((d>>2)&7)
  const int b = blockIdx.x >> 1;
  const int d0 = (blockIdx.x & 1) * 64;
  const int t = threadIdx.x;
  const float* hsbase = hs + (size_t)b * SENC * H_;

  // phase 1: stage hs (128x128) and this half's cat rows (64x128), swizzled
  for (int i = t; i < 4096; i += 256) {
    int r = i >> 5, c4 = i & 31;
    int pc = c4 ^ ((r >> 3) & 3);
    *(f32x4*)&hsb[r][pc * 4] = *(const f32x4*)(hsbase + r * H_ + c4 * 4);
  }
  for (int i = t; i < 2048; i += 256) {
    int r = i >> 5, c4 = i & 31;
    int pc = c4 ^ ((r >> 2) & 7);
    *(f32x4*)&ctb[r][pc * 4] =
        *(const f32x4*)(cat + (size_t)(b * SDEC + d0 + r) * 256 + c4 * 4);
  }
  __syncthreads();

  // phase 2: scores s[e][d] -> sbuf[d][e]; 8e x 4d per thread, b128 k-chunks
  {
    const int te = t >> 4, td = t & 15;
    const int sa = te & 3, sb2 = td & 7;
    float acc[8][4] = {};
    for (int k4 = 0; k4 < 32; k4++) {
      const int pa = (k4 ^ sa) * 4, pb = (k4 ^ sb2) * 4;
      f32x4 av[8], bv[4];
#pragma unroll
      for (int i = 0; i < 8; i++) av[i] = *(const f32x4*)&hsb[te * 8 + i][pa];
#pragma unroll
      for (int j = 0; j < 4; j++) bv[j] = *(const f32x4*)&ctb[td * 4 + j][pb];
#pragma unroll
      for (int i = 0; i < 8; i++)
#pragma unroll
        for (int j = 0; j < 4; j++)
          acc[i][j] += av[i][0] * bv[j][0] + av[i][1] * bv[j][1] +
                       av[i][2] * bv[j][2] + av[i][3] * bv[j][3];
    }
    const int swd = td & 7;
#pragma unroll
    for (int j = 0; j < 4; j++) {
      int drow = td * 4 + j;
      f32x4 v0 = {acc[0][j], acc[1][j], acc[2][j], acc[3][j]};
      f32x4 v1 = {acc[4][j], acc[5][j], acc[6][j], acc[7][j]};
      *(f32x4*)&sbuf[drow][((te * 2) ^ swd) * 4] = v0;
      *(f32x4*)&sbuf[drow][((te * 2 + 1) ^ swd) * 4] = v1;
    }
  }
  __syncthreads();

  // phase 3: softmax along e for each d-row; 4 threads per row, shfl-reduce
  {
    const int d = t >> 2, p = t & 3;
    const int swz = (d >> 2) & 7;
    f32x4 vals[8];
    float mx = -1e30f;
#pragma unroll
    for (int mm = 0; mm < 8; mm++) {
      int pc = p * 8 + mm;
      f32x4 v = *(const f32x4*)&sbuf[d][pc * 4];
      vals[mm] = v;
      mx = fmaxf(mx, fmaxf(fmaxf(v[0], v[1]), fmaxf(v[2], v[3])));
    }
    mx = fmaxf(mx, __shfl_xor(mx, 1));
    mx = fmaxf(mx, __shfl_xor(mx, 2));
    float sum = 0.f;
#pragma unroll
    for (int mm = 0; mm < 8; mm++) {
      f32x4 v = vals[mm];
      v[0] = __expf(v[0] - mx); v[1] = __expf(v[1] - mx);
      v[2] = __expf(v[2] - mx); v[3] = __expf(v[3] - mx);
      vals[mm] = v;
      sum += v[0] + v[1] + v[2] + v[3];
    }
    sum += __shfl_xor(sum, 1); sum += __shfl_xor(sum, 2);
    const float inv = 1.f / sum;
    float* aw = attw_out + (size_t)b * SENC * SDEC + d0 + d;
#pragma unroll
    for (int mm = 0; mm < 8; mm++) {
      int pc = p * 8 + mm;
      f32x4 v = vals[mm];
      v[0] *= inv; v[1] *= inv; v[2] *= inv; v[3] *= inv;
      *(f32x4*)&sbuf[d][pc * 4] = v;
      int c4 = pc ^ swz;  // logical e-chunk
#pragma unroll
      for (int u = 0; u < 4; u++)
        aw[(size_t)(c4 * 4 + u) * SDEC] = v[u];
    }
  }
  __syncthreads();

  // phase 4: c[d][h] = sum_e P[d][e] * hs[e][h]; 4d x 8h per thread
  {
    const int td = t >> 4, th = t & 15;
    const int swd = td & 7;
    float acc[4][8] = {};
    for (int e4 = 0; e4 < 32; e4++) {
      const int pp = (e4 ^ swd) * 4;
      f32x4 pv[4];
#pragma unroll
      for (int i = 0; i < 4; i++) pv[i] = *(const f32x4*)&sbuf[td * 4 + i][pp];
#pragma unroll
      for (int j = 0; j < 4; j++) {
        int e = e4 * 4 + j;
        int sw = (e >> 3) & 3;
        f32x4 h0v = *(const f32x4*)&hsb[e][((th * 2) ^ sw) * 4];
        f32x4 h1v = *(const f32x4*)&hsb[e][((th * 2 + 1) ^ sw) * 4];
#pragma unroll
        for (int i = 0; i < 4; i++) {
          float pw = pv[i][j];
          acc[i][0] += pw * h0v[0]; acc[i][1] += pw * h0v[1];
          acc[i][2] += pw * h0v[2]; acc[i][3] += pw * h0v[3];
          acc[i][4] += pw * h1v[0]; acc[i][5] += pw * h1v[1];
          acc[i][6] += pw * h1v[2]; acc[i][7] += pw * h1v[3];
        }
      }
    }
#pragma unroll
    for (int i = 0; i < 4; i++) {
      union { __hip_bfloat16 hv[8]; uint4 v; } pk;
#pragma unroll
      for (int u = 0; u < 8; u++) pk.hv[u] = __float2bfloat16(acc[i][u]);
      *(uint4*)(cat_bf + (size_t)(b * SDEC + d0 + td * 4 + i) * 256 + 128 +
                th * 8) = pk.v;
    }
  }
}

// ---------------------------------------------------------------------------
// Kernel 4: logits = cat @ w_out^T + b_out   (unchanged — near write-BW floor)
// ---------------------------------------------------------------------------
__global__ __launch_bounds__(512) void k_gemm_mfma(
    const __hip_bfloat16* __restrict__ A, const __hip_bfloat16* __restrict__ Bw,
    const float* __restrict__ b_out, float* __restrict__ C) {
  constexpr int K = 256, N = V_, Kt = 32;
  alignas(16) __shared__ char smem[73728];  // 72 KB
  __hip_bfloat16 (*As)[4096] = (__hip_bfloat16(*)[4096])smem;            // [3][128*32]
  __hip_bfloat16 (*Bs)[8192] = (__hip_bfloat16(*)[8192])(smem + 24576);  // [3][256*32]
  float* tr = (float*)smem;  // epilogue: [64][260] padded f32 half-tile

  const int tid = threadIdx.x;
  const int w = tid >> 6, l = tid & 63;
  const int wr = w >> 2, wc = w & 3;       // 2M x 4N waves, each 64x64
  const int lr = l & 15, lk = l >> 4;
  const int lq = l >> 2, lc = l & 3;

  const int bid = blockIdx.x;
  const int wgid = (bid & 7) * 500 + (bid >> 3);
  const int mt = wgid & 31;
  const int nt = wgid >> 5;
  const int m0 = mt * 128, n0 = nt * 256;

  f32x4 acc[4][4];
#pragma unroll
  for (int m = 0; m < 4; m++)
#pragma unroll
    for (int n = 0; n < 4; n++) acc[m][n] = (f32x4){0.f, 0.f, 0.f, 0.f};

#define STAGE(buf, kk)                                                            \
  do {                                                                            \
    const __hip_bfloat16* gA = A + (size_t)(m0 + w * 16 + lq) * K + (kk) + lc * 8;\
    const __hip_bfloat16* gB0 = Bw + (size_t)(n0 + w * 32 + lq) * K + (kk) + lc * 8;\
    const __hip_bfloat16* gB1 = gB0 + (size_t)16 * K;                             \
    __builtin_amdgcn_global_load_lds((const GLOBAL_AS void*)gA,                   \
        (LDS_AS void*)(&As[buf][w * 512]), 16, 0, 0);                             \
    __builtin_amdgcn_global_load_lds((const GLOBAL_AS void*)gB0,                  \
        (LDS_AS void*)(&Bs[buf][w * 1024]), 16, 0, 0);                            \
    __builtin_amdgcn_global_load_lds((const GLOBAL_AS void*)gB1,                  \
        (LDS_AS void*)(&Bs[buf][w * 1024 + 512]), 16, 0, 0);                      \
  } while (0)

  STAGE(0, 0);
  STAGE(1, Kt);

#pragma unroll
  for (int t = 0; t < 8; ++t) {
    if (t < 7) asm volatile("s_waitcnt vmcnt(3)" ::: "memory");
    else       asm volatile("s_waitcnt vmcnt(0)" ::: "memory");
    __builtin_amdgcn_s_barrier();
    asm volatile("" ::: "memory");

    const int c = t % 3;
    bf16x8 af[4], bfr[4];
#pragma unroll
    for (int m = 0; m < 4; m++)
      af[m] = *(const bf16x8*)(const void*)(&As[c][(wr * 64 + m * 16 + lr) * Kt + lk * 8]);
#pragma unroll
    for (int n = 0; n < 4; n++)
      bfr[n] = *(const bf16x8*)(const void*)(&Bs[c][(wc * 64 + n * 16 + lr) * Kt + lk * 8]);

    if (t < 6) STAGE((t + 2) % 3, (t + 2) * Kt);

#pragma unroll
    for (int m = 0; m < 4; m++)
#pragma unroll
      for (int n = 0; n < 4; n++)
        acc[m][n] = __builtin_amdgcn_mfma_f32_16x16x32_bf16(bfr[n], af[m], acc[m][n], 0, 0, 0);
  }
#undef STAGE

  __syncthreads();
#pragma unroll
  for (int h = 0; h < 2; ++h) {
    if (wr == h) {
#pragma unroll
      for (int m = 0; m < 4; m++) {
#pragma unroll
        for (int n = 0; n < 4; n++) {
          const int row = m * 16 + lr;
          const int col = wc * 64 + n * 16 + lk * 4;
          const float4 bo = *(const float4*)(b_out + n0 + col);
          f32x4 v;
          v[0] = acc[m][n][0] + bo.x;
          v[1] = acc[m][n][1] + bo.y;
          v[2] = acc[m][n][2] + bo.z;
          v[3] = acc[m][n][3] + bo.w;
          *(f32x4*)&tr[row * 260 + col] = v;
        }
      }
    }
    __syncthreads();
#pragma unroll
    for (int i = 0; i < 8; ++i) {
      const int c2 = i * 512 + tid;
      const int row = c2 >> 6;
      const int off = (c2 & 63) * 4;
      f32x4 v = *(const f32x4*)&tr[row * 260 + off];
      __builtin_nontemporal_store(
          v, (f32x4*)(C + (size_t)(m0 + h * 64 + row) * N + n0 + off));
    }
    __syncthreads();
  }
}

// ---------------------------------------------------------------------------
extern "C" void kernel_launch(void* const* d_in, const int* in_sizes, int n_in,
                              void* d_out, int out_size, void* d_ws, size_t ws_size,
                              hipStream_t stream) {
  const int* seq = (const int*)d_in[0];
  const float* hs = (const float*)d_in[1];
  const float* h0 = (const float*)d_in[2];
  const float* emb = (const float*)d_in[3];
  const float* w_ih = (const float*)d_in[4];
  const float* w_hh = (const float*)d_in[5];
  const float* b_ih = (const float*)d_in[6];
  const float* b_hh = (const float*)d_in[7];
  const float* w_out = (const float*)d_in[8];
  const float* b_out = (const float*)d_in[9];

  float* out = (float*)d_out;
  float* logits = out;                          // 131,072,000 f32
  float* state = out + 131072000;               // 4,096 f32
  float* attw = out + 131072000 + 4096;         // 524,288 f32

  char* ws = (char*)d_ws;
  float* xg = (float*)ws;                              // 6,291,456 B
  float* cat = (float*)(ws + 6291456);                 // 4,194,304 B
  __hip_bfloat16* cat_bf = (__hip_bfloat16*)(ws + 10485760);   // 2,097,152 B
  __hip_bfloat16* wout_bf = (__hip_bfloat16*)(ws + 12582912);  // 16,384,000 B

  k_embed_proj<<<256, 192, 0, stream>>>(seq, emb, w_ih, b_ih, xg);
  k_gru_cvt<<<2032, 512, 0, stream>>>(xg, h0, w_hh, b_hh, cat, cat_bf, state,
                                      w_out, wout_bf);
  k_attn<<<64, 256, 0, stream>>>(hs, cat, attw, cat_bf);
  k_gemm_mfma<<<4000, 512, 0, stream>>>(cat_bf, wout_bf, b_out, logits);
}

// Round 3
// 252.188 us; speedup vs baseline: 1.4407x; 1.0840x over previous
//
#include <hip/hip_runtime.h>
#include <hip/hip_bf16.h>

#define B_    32
#define SDEC  128
#define SENC  128
#define V_    32000
#define E_    200
#define H_    128
#define G3    384   // 3*H

typedef __attribute__((ext_vector_type(8))) short bf16x8;
typedef __attribute__((ext_vector_type(4))) float f32x4;
typedef __attribute__((ext_vector_type(2))) float f32x2;

#define GLOBAL_AS __attribute__((address_space(1)))
#define LDS_AS    __attribute__((address_space(3)))

__device__ __forceinline__ float fast_sigmoid(float x) {
  return 1.f / (1.f + __expf(-x));
}
__device__ __forceinline__ float fast_tanh(float x) {
  float e2 = __expf(2.f * x);
  return 1.f - 2.f / (e2 + 1.f);
}

// ---------------------------------------------------------------------------
// Kernel 1: x = emb[seq]; xg = x @ w_ih^T + b_ih   -> xg [4096][384] f32
// ---------------------------------------------------------------------------
__global__ __launch_bounds__(192) void k_embed_proj(
    const int* __restrict__ seq, const float* __restrict__ emb,
    const float* __restrict__ w_ih, const float* __restrict__ b_ih,
    float* __restrict__ xg) {
  __shared__ __align__(16) float xs[16][E_];
  __shared__ int sidx[16];
  const int r0 = blockIdx.x * 16;
  const int t = threadIdx.x;
  if (t < 16) sidx[t] = seq[r0 + t];
  __syncthreads();
  for (int i = t; i < 800; i += 192) {
    int r = i / 50, c = i - r * 50;
    *(float4*)&xs[r][c * 4] =
        *(const float4*)(emb + (size_t)sidx[r] * E_ + c * 4);
  }
  __syncthreads();
  const int g0 = t, g1 = t + 192;
  float a0[16], a1[16];
#pragma unroll
  for (int r = 0; r < 16; r++) { a0[r] = 0.f; a1[r] = 0.f; }
  const float* w0 = w_ih + (size_t)g0 * E_;
  const float* w1 = w_ih + (size_t)g1 * E_;
  for (int k = 0; k < E_; k += 4) {
    float4 wv0 = *(const float4*)(w0 + k);
    float4 wv1 = *(const float4*)(w1 + k);
#pragma unroll
    for (int r = 0; r < 16; r++) {
      float4 xv = *(const float4*)&xs[r][k];
      a0[r] += wv0.x * xv.x + wv0.y * xv.y + wv0.z * xv.z + wv0.w * xv.w;
      a1[r] += wv1.x * xv.x + wv1.y * xv.y + wv1.z * xv.z + wv1.w * xv.w;
    }
  }
  const float b0 = b_ih[g0], b1 = b_ih[g1];
#pragma unroll
  for (int r = 0; r < 16; r++) {
    xg[(size_t)(r0 + r) * G3 + g0] = a0[r] + b0;
    xg[(size_t)(r0 + r) * G3 + g1] = a1[r] + b1;
  }
}

// ---------------------------------------------------------------------------
// Kernel 2: fused GRU scan (blocks 0..31) + w_out f32->bf16 (blocks 32..2031).
// Matvec now in f32x2 vectors (targets v_pk_fma_f32). Single barrier/step.
// ---------------------------------------------------------------------------
__global__ __launch_bounds__(512) void k_gru_cvt(
    const float* __restrict__ xg, const float* __restrict__ h0,
    const float* __restrict__ w_hh, const float* __restrict__ b_hh,
    __hip_bfloat16* __restrict__ cat_bf, float* __restrict__ state_out,
    const float* __restrict__ w_out, __hip_bfloat16* __restrict__ wout_bf) {
  if (blockIdx.x >= 32) {
    int idx = ((blockIdx.x - 32) * 512 + threadIdx.x) * 8;
    float4 a = *(const float4*)(w_out + idx);
    float4 c = *(const float4*)(w_out + idx + 4);
    union { __hip_bfloat16 h[8]; uint4 v; } p;
    p.h[0] = __float2bfloat16(a.x); p.h[1] = __float2bfloat16(a.y);
    p.h[2] = __float2bfloat16(a.z); p.h[3] = __float2bfloat16(a.w);
    p.h[4] = __float2bfloat16(c.x); p.h[5] = __float2bfloat16(c.y);
    p.h[6] = __float2bfloat16(c.z); p.h[7] = __float2bfloat16(c.w);
    *(uint4*)(wout_bf + idx) = p.v;
    return;
  }

  const int b = blockIdx.x;
  const int t = threadIdx.x;
  const int hh = t >> 2;   // owned h element
  const int sub = t & 3;   // k-quarter

  float wr_[32], wz_[32], wn_[32];
#pragma unroll
  for (int m = 0; m < 8; m++) {
    int c = (m + sub * 2) & 7;
    int kb = sub * 32 + c * 4;
    *(float4*)&wr_[m * 4] = *(const float4*)(w_hh + (size_t)hh * H_ + kb);
    *(float4*)&wz_[m * 4] = *(const float4*)(w_hh + (size_t)(128 + hh) * H_ + kb);
    *(float4*)&wn_[m * 4] = *(const float4*)(w_hh + (size_t)(256 + hh) * H_ + kb);
  }

  __shared__ __align__(16) float hp[2][H_];
  const float* xgb = xg + (size_t)b * SDEC * G3;
  const float br = b_hh[hh], bz = b_hh[128 + hh], bn = b_hh[256 + hh];
  float cxr = xgb[hh], cxz = xgb[128 + hh], cxn = xgb[256 + hh];
  if (t < H_) hp[0][t] = h0[b * H_ + t];
  __hip_bfloat16* catbfb = cat_bf + (size_t)b * SDEC * 256;
  __syncthreads();

  int cur = 0;
  for (int s = 0; s < SDEC; s++) {
    float nxr = 0.f, nxz = 0.f, nxn = 0.f;
    if (s + 1 < SDEC) {
      const float* xp = xgb + (size_t)(s + 1) * G3;
      nxr = xp[hh]; nxz = xp[128 + hh]; nxn = xp[256 + hh];
    }
    f32x2 sr2 = {0.f, 0.f}, sz2 = {0.f, 0.f}, sn2 = {0.f, 0.f};
#pragma unroll
    for (int m = 0; m < 8; m++) {
      int c = (m + sub * 2) & 7;
      float4 hv = *(const float4*)&hp[cur][sub * 32 + c * 4];
      f32x2 h01 = {hv.x, hv.y}, h23 = {hv.z, hv.w};
      const f32x2* w2r = (const f32x2*)&wr_[m * 4];
      const f32x2* w2z = (const f32x2*)&wz_[m * 4];
      const f32x2* w2n = (const f32x2*)&wn_[m * 4];
      sr2 += w2r[0] * h01; sr2 += w2r[1] * h23;
      sz2 += w2z[0] * h01; sz2 += w2z[1] * h23;
      sn2 += w2n[0] * h01; sn2 += w2n[1] * h23;
    }
    float sr = sr2[0] + sr2[1];
    float sz = sz2[0] + sz2[1];
    float sn = sn2[0] + sn2[1];
    sr += __shfl_xor(sr, 1); sr += __shfl_xor(sr, 2);
    sz += __shfl_xor(sz, 1); sz += __shfl_xor(sz, 2);
    sn += __shfl_xor(sn, 1); sn += __shfl_xor(sn, 2);

    float hold = hp[cur][hh];
    float r = fast_sigmoid(cxr + sr + br);
    float z = fast_sigmoid(cxz + sz + bz);
    float n = fast_tanh(cxn + r * (sn + bn));
    float hnew = (1.f - z) * n + z * hold;
    if (sub == 0) {
      hp[cur ^ 1][hh] = hnew;
      catbfb[(size_t)s * 256 + hh] = __float2bfloat16(hnew);
    }
    __syncthreads();
    cur ^= 1;
    cxr = nxr; cxz = nxz; cxn = nxn;
  }
  if (t < H_) state_out[b * H_ + t] = hp[cur][t];
}

// ---------------------------------------------------------------------------
// Kernel 3: attention via MFMA. 32 blocks (one per batch) x 512 thr (8 waves).
// Wave w owns d-tile w (rows d = w*16+lr). Scores S[d][e] = mfma(hs, ct);
// softmax fully in-register; P -> swizzled LDS -> A-fragments; context via
// column-rotated hsT (rot = 8*(h&15)), conflict-free staging and reads.
// ---------------------------------------------------------------------------
__global__ __launch_bounds__(512) void k_attn_mfma(
    const float* __restrict__ hs, __hip_bfloat16* __restrict__ cat_bf,
    float* __restrict__ attw_out) {
  __shared__ __hip_bfloat16 hsb[128][128];   // hs rows,  chunk c ^ (e&7)
  __shared__ __hip_bfloat16 hsT[128][128];   // hs^T, col' = (e + 8*(h&15))&127
  __shared__ __hip_bfloat16 ctb[128][128];   // output rows, chunk c ^ (d&7)
  __shared__ __hip_bfloat16 plds[128][128];  // P rows, chunk c ^ (d&7)
  const int b = blockIdx.x;
  const int t = threadIdx.x;
  const int w = t >> 6, l = t & 63;
  const int lr = l & 15, lk = l >> 4;
  const float* hsbase = hs + (size_t)b * SENC * H_;

  // ---- stage A: ct (bf16 copy of GRU output) + hs (f32 -> bf16) ----------
  for (int i = t; i < 2048; i += 512) {
    int d = i >> 4, c = i & 15;
    uint4 v = *(const uint4*)(cat_bf + (size_t)(b * SDEC + d) * 256 + c * 8);
    *(uint4*)&ctb[d][((c ^ (d & 7)) * 8)] = v;
  }
  for (int i = t; i < 2048; i += 512) {
    int e = i >> 4, c = i & 15;
    float4 v0 = *(const float4*)(hsbase + e * H_ + c * 8);
    float4 v1 = *(const float4*)(hsbase + e * H_ + c * 8 + 4);
    union { __hip_bfloat16 h[8]; uint4 u; } pk;
    pk.h[0] = __float2bfloat16(v0.x); pk.h[1] = __float2bfloat16(v0.y);
    pk.h[2] = __float2bfloat16(v0.z); pk.h[3] = __float2bfloat16(v0.w);
    pk.h[4] = __float2bfloat16(v1.x); pk.h[5] = __float2bfloat16(v1.y);
    pk.h[6] = __float2bfloat16(v1.z); pk.h[7] = __float2bfloat16(v1.w);
    *(uint4*)&hsb[e][((c ^ (e & 7)) * 8)] = pk.u;
  }
  __syncthreads();

  // ---- pass B: build rotated hs^T from hsb (e-major lanes: merge-free) ----
  for (int i = t; i < 2048; i += 512) {
    int c = i >> 7, e = i & 127;
    uint4 v = *(const uint4*)&hsb[e][((c ^ (e & 7)) * 8)];
    const __hip_bfloat16* hv = (const __hip_bfloat16*)&v;
#pragma unroll
    for (int u = 0; u < 8; u++) {
      int h = c * 8 + u;
      int col = (e + 8 * (h & 15)) & 127;
      hsT[h][col] = hv[u];
    }
  }
  __syncthreads();

  // ---- phase 2: scores S[d][e], d-tile w, 8 e-tiles x 4 k-steps -----------
  f32x4 acc[8];
#pragma unroll
  for (int et = 0; et < 8; et++) acc[et] = (f32x4){0.f, 0.f, 0.f, 0.f};
  bf16x8 afrag[4];
#pragma unroll
  for (int kt = 0; kt < 4; kt++)
    afrag[kt] = *(const bf16x8*)&ctb[w * 16 + lr][(((kt * 4 + lk) ^ (lr & 7)) * 8)];
#pragma unroll
  for (int et = 0; et < 8; et++) {
#pragma unroll
    for (int kt = 0; kt < 4; kt++) {
      bf16x8 bfrag =
          *(const bf16x8*)&hsb[et * 16 + lr][(((kt * 4 + lk) ^ (lr & 7)) * 8)];
      acc[et] =
          __builtin_amdgcn_mfma_f32_16x16x32_bf16(bfrag, afrag[kt], acc[et], 0, 0, 0);
    }
  }

  // ---- phase 3: softmax over e, fully in-register -------------------------
  float mx = -1e30f;
#pragma unroll
  for (int et = 0; et < 8; et++) {
    mx = fmaxf(mx, fmaxf(fmaxf(acc[et][0], acc[et][1]),
                         fmaxf(acc[et][2], acc[et][3])));
  }
  mx = fmaxf(mx, __shfl_xor(mx, 16));
  mx = fmaxf(mx, __shfl_xor(mx, 32));
  float sum = 0.f;
#pragma unroll
  for (int et = 0; et < 8; et++) {
    acc[et][0] = __expf(acc[et][0] - mx);
    acc[et][1] = __expf(acc[et][1] - mx);
    acc[et][2] = __expf(acc[et][2] - mx);
    acc[et][3] = __expf(acc[et][3] - mx);
    sum += acc[et][0] + acc[et][1] + acc[et][2] + acc[et][3];
  }
  sum += __shfl_xor(sum, 16);
  sum += __shfl_xor(sum, 32);
  const float inv = 1.f / sum;

  // ---- write P (bf16, swizzled LDS) + attw (f32, 64B-run coalesced) -------
  const int d = w * 16 + lr;
  float* aw = attw_out + (size_t)b * SENC * SDEC + d;
#pragma unroll
  for (int et = 0; et < 8; et++) {
    acc[et][0] *= inv; acc[et][1] *= inv;
    acc[et][2] *= inv; acc[et][3] *= inv;
    union { __hip_bfloat16 h[4]; uint2 u; } pk4;
    pk4.h[0] = __float2bfloat16(acc[et][0]);
    pk4.h[1] = __float2bfloat16(acc[et][1]);
    pk4.h[2] = __float2bfloat16(acc[et][2]);
    pk4.h[3] = __float2bfloat16(acc[et][3]);
    *(uint2*)&plds[d][(((et * 2 + (lk >> 1)) ^ (lr & 7)) * 8 + 4 * (lk & 1))] =
        pk4.u;
    const int e0 = et * 16 + lk * 4;
#pragma unroll
    for (int j = 0; j < 4; j++)
      aw[(size_t)(e0 + j) * SDEC] = acc[et][j];
  }
  __syncthreads();

  // ---- phase 4: context c[d][h] = P @ hs, 8 h-tiles x 4 k(e)-steps --------
  bf16x8 pfrag[4];
#pragma unroll
  for (int f = 0; f < 4; f++)
    pfrag[f] = *(const bf16x8*)&plds[d][(((f * 4 + lk) ^ (lr & 7)) * 8)];
#pragma unroll
  for (int ht = 0; ht < 8; ht++) {
    f32x4 a2 = (f32x4){0.f, 0.f, 0.f, 0.f};
#pragma unroll
    for (int kt = 0; kt < 4; kt++) {
      bf16x8 hfrag =
          *(const bf16x8*)&hsT[ht * 16 + lr][((kt * 32 + lk * 8 + 8 * lr) & 127)];
      a2 = __builtin_amdgcn_mfma_f32_16x16x32_bf16(hfrag, pfrag[kt], a2, 0, 0, 0);
    }
    union { __hip_bfloat16 h[4]; uint2 u; } pk4;
    pk4.h[0] = __float2bfloat16(a2[0]);
    pk4.h[1] = __float2bfloat16(a2[1]);
    pk4.h[2] = __float2bfloat16(a2[2]);
    pk4.h[3] = __float2bfloat16(a2[3]);
    *(uint2*)(cat_bf + (size_t)(b * SDEC + d) * 256 + 128 + ht * 16 + lk * 4) =
        pk4.u;
  }
}

// ---------------------------------------------------------------------------
// Kernel 4: logits = cat @ w_out^T + b_out   (unchanged — near write-BW floor)
// ---------------------------------------------------------------------------
__global__ __launch_bounds__(512) void k_gemm_mfma(
    const __hip_bfloat16* __restrict__ A, const __hip_bfloat16* __restrict__ Bw,
    const float* __restrict__ b_out, float* __restrict__ C) {
  constexpr int K = 256, N = V_, Kt = 32;
  alignas(16) __shared__ char smem[73728];  // 72 KB
  __hip_bfloat16 (*As)[4096] = (__hip_bfloat16(*)[4096])smem;            // [3][128*32]
  __hip_bfloat16 (*Bs)[8192] = (__hip_bfloat16(*)[8192])(smem + 24576);  // [3][256*32]
  float* tr = (float*)smem;  // epilogue: [64][260] padded f32 half-tile

  const int tid = threadIdx.x;
  const int w = tid >> 6, l = tid & 63;
  const int wr = w >> 2, wc = w & 3;       // 2M x 4N waves, each 64x64
  const int lr = l & 15, lk = l >> 4;
  const int lq = l >> 2, lc = l & 3;

  const int bid = blockIdx.x;
  const int wgid = (bid & 7) * 500 + (bid >> 3);
  const int mt = wgid & 31;
  const int nt = wgid >> 5;
  const int m0 = mt * 128, n0 = nt * 256;

  f32x4 acc[4][4];
#pragma unroll
  for (int m = 0; m < 4; m++)
#pragma unroll
    for (int n = 0; n < 4; n++) acc[m][n] = (f32x4){0.f, 0.f, 0.f, 0.f};

#define STAGE(buf, kk)                                                            \
  do {                                                                            \
    const __hip_bfloat16* gA = A + (size_t)(m0 + w * 16 + lq) * K + (kk) + lc * 8;\
    const __hip_bfloat16* gB0 = Bw + (size_t)(n0 + w * 32 + lq) * K + (kk) + lc * 8;\
    const __hip_bfloat16* gB1 = gB0 + (size_t)16 * K;                             \
    __builtin_amdgcn_global_load_lds((const GLOBAL_AS void*)gA,                   \
        (LDS_AS void*)(&As[buf][w * 512]), 16, 0, 0);                             \
    __builtin_amdgcn_global_load_lds((const GLOBAL_AS void*)gB0,                  \
        (LDS_AS void*)(&Bs[buf][w * 1024]), 16, 0, 0);                            \
    __builtin_amdgcn_global_load_lds((const GLOBAL_AS void*)gB1,                  \
        (LDS_AS void*)(&Bs[buf][w * 1024 + 512]), 16, 0, 0);                      \
  } while (0)

  STAGE(0, 0);
  STAGE(1, Kt);

#pragma unroll
  for (int t = 0; t < 8; ++t) {
    if (t < 7) asm volatile("s_waitcnt vmcnt(3)" ::: "memory");
    else       asm volatile("s_waitcnt vmcnt(0)" ::: "memory");
    __builtin_amdgcn_s_barrier();
    asm volatile("" ::: "memory");

    const int c = t % 3;
    bf16x8 af[4], bfr[4];
#pragma unroll
    for (int m = 0; m < 4; m++)
      af[m] = *(const bf16x8*)(const void*)(&As[c][(wr * 64 + m * 16 + lr) * Kt + lk * 8]);
#pragma unroll
    for (int n = 0; n < 4; n++)
      bfr[n] = *(const bf16x8*)(const void*)(&Bs[c][(wc * 64 + n * 16 + lr) * Kt + lk * 8]);

    if (t < 6) STAGE((t + 2) % 3, (t + 2) * Kt);

#pragma unroll
    for (int m = 0; m < 4; m++)
#pragma unroll
      for (int n = 0; n < 4; n++)
        acc[m][n] = __builtin_amdgcn_mfma_f32_16x16x32_bf16(bfr[n], af[m], acc[m][n], 0, 0, 0);
  }
#undef STAGE

  __syncthreads();
#pragma unroll
  for (int h = 0; h < 2; ++h) {
    if (wr == h) {
#pragma unroll
      for (int m = 0; m < 4; m++) {
#pragma unroll
        for (int n = 0; n < 4; n++) {
          const int row = m * 16 + lr;
          const int col = wc * 64 + n * 16 + lk * 4;
          const float4 bo = *(const float4*)(b_out + n0 + col);
          f32x4 v;
          v[0] = acc[m][n][0] + bo.x;
          v[1] = acc[m][n][1] + bo.y;
          v[2] = acc[m][n][2] + bo.z;
          v[3] = acc[m][n][3] + bo.w;
          *(f32x4*)&tr[row * 260 + col] = v;
        }
      }
    }
    __syncthreads();
#pragma unroll
    for (int i = 0; i < 8; ++i) {
      const int c2 = i * 512 + tid;
      const int row = c2 >> 6;
      const int off = (c2 & 63) * 4;
      f32x4 v = *(const f32x4*)&tr[row * 260 + off];
      __builtin_nontemporal_store(
          v, (f32x4*)(C + (size_t)(m0 + h * 64 + row) * N + n0 + off));
    }
    __syncthreads();
  }
}

// ---------------------------------------------------------------------------
extern "C" void kernel_launch(void* const* d_in, const int* in_sizes, int n_in,
                              void* d_out, int out_size, void* d_ws, size_t ws_size,
                              hipStream_t stream) {
  const int* seq = (const int*)d_in[0];
  const float* hs = (const float*)d_in[1];
  const float* h0 = (const float*)d_in[2];
  const float* emb = (const float*)d_in[3];
  const float* w_ih = (const float*)d_in[4];
  const float* w_hh = (const float*)d_in[5];
  const float* b_ih = (const float*)d_in[6];
  const float* b_hh = (const float*)d_in[7];
  const float* w_out = (const float*)d_in[8];
  const float* b_out = (const float*)d_in[9];

  float* out = (float*)d_out;
  float* logits = out;                          // 131,072,000 f32
  float* state = out + 131072000;               // 4,096 f32
  float* attw = out + 131072000 + 4096;         // 524,288 f32

  char* ws = (char*)d_ws;
  float* xg = (float*)ws;                              // 6,291,456 B
  __hip_bfloat16* cat_bf = (__hip_bfloat16*)(ws + 10485760);   // 2,097,152 B
  __hip_bfloat16* wout_bf = (__hip_bfloat16*)(ws + 12582912);  // 16,384,000 B

  k_embed_proj<<<256, 192, 0, stream>>>(seq, emb, w_ih, b_ih, xg);
  k_gru_cvt<<<2032, 512, 0, stream>>>(xg, h0, w_hh, b_hh, cat_bf, state,
                                      w_out, wout_bf);
  k_attn_mfma<<<32, 512, 0, stream>>>(hs, cat_bf, attw);
  k_gemm_mfma<<<4000, 512, 0, stream>>>(cat_bf, wout_bf, b_out, logits);
}

// Round 4
// 251.816 us; speedup vs baseline: 1.4428x; 1.0015x over previous
//
#include <hip/hip_runtime.h>
#include <hip/hip_bf16.h>

#define B_    32
#define SDEC  128
#define SENC  128
#define V_    32000
#define E_    200
#define H_    128
#define G3    384   // 3*H

typedef __attribute__((ext_vector_type(8))) short bf16x8;
typedef __attribute__((ext_vector_type(4))) float f32x4;
typedef __attribute__((ext_vector_type(2))) float f32x2;

#define GLOBAL_AS __attribute__((address_space(1)))
#define LDS_AS    __attribute__((address_space(3)))

__device__ __forceinline__ float fast_sigmoid(float x) {
  return 1.f / (1.f + __expf(-x));
}
__device__ __forceinline__ float fast_tanh(float x) {
  float e2 = __expf(2.f * x);
  return 1.f - 2.f / (e2 + 1.f);
}
// butterfly sum over each aligned 4-lane quad, pure VALU (DPP quad_perm)
__device__ __forceinline__ float quad_reduce(float x) {
  int i = __builtin_bit_cast(int, x);
  int a = __builtin_amdgcn_mov_dpp(i, 0xB1, 0xF, 0xF, true);  // xor 1
  float s = x + __builtin_bit_cast(float, a);
  int j = __builtin_bit_cast(int, s);
  int c = __builtin_amdgcn_mov_dpp(j, 0x4E, 0xF, 0xF, true);  // xor 2
  return s + __builtin_bit_cast(float, c);
}

// ---------------------------------------------------------------------------
// Kernel 1: x = emb[seq]; xg = x @ w_ih^T + b_ih   -> xg [4096][384] f32
// ---------------------------------------------------------------------------
__global__ __launch_bounds__(192) void k_embed_proj(
    const int* __restrict__ seq, const float* __restrict__ emb,
    const float* __restrict__ w_ih, const float* __restrict__ b_ih,
    float* __restrict__ xg) {
  __shared__ __align__(16) float xs[16][E_];
  __shared__ int sidx[16];
  const int r0 = blockIdx.x * 16;
  const int t = threadIdx.x;
  if (t < 16) sidx[t] = seq[r0 + t];
  __syncthreads();
  for (int i = t; i < 800; i += 192) {
    int r = i / 50, c = i - r * 50;
    *(float4*)&xs[r][c * 4] =
        *(const float4*)(emb + (size_t)sidx[r] * E_ + c * 4);
  }
  __syncthreads();
  const int g0 = t, g1 = t + 192;
  float a0[16], a1[16];
#pragma unroll
  for (int r = 0; r < 16; r++) { a0[r] = 0.f; a1[r] = 0.f; }
  const float* w0 = w_ih + (size_t)g0 * E_;
  const float* w1 = w_ih + (size_t)g1 * E_;
  for (int k = 0; k < E_; k += 4) {
    float4 wv0 = *(const float4*)(w0 + k);
    float4 wv1 = *(const float4*)(w1 + k);
#pragma unroll
    for (int r = 0; r < 16; r++) {
      float4 xv = *(const float4*)&xs[r][k];
      a0[r] += wv0.x * xv.x + wv0.y * xv.y + wv0.z * xv.z + wv0.w * xv.w;
      a1[r] += wv1.x * xv.x + wv1.y * xv.y + wv1.z * xv.z + wv1.w * xv.w;
    }
  }
  const float b0 = b_ih[g0], b1 = b_ih[g1];
#pragma unroll
  for (int r = 0; r < 16; r++) {
    xg[(size_t)(r0 + r) * G3 + g0] = a0[r] + b0;
    xg[(size_t)(r0 + r) * G3 + g1] = a1[r] + b1;
  }
}

// ---------------------------------------------------------------------------
// Kernel 2: blocks 0..31  : GRU scan + fused MFMA attention (one batch each)
//           blocks 32..2031: w_out f32->bf16 convert (hidden under the scan)
// Scan: DPP quad-reduce (no DS shuffles), raw s_barrier + lgkmcnt(0) only
// (no vmcnt drain -> xg prefetch truly overlaps). GRU output kept in LDS
// ctb in MFMA-fragment swizzled layout; attention runs in the same block.
// ---------------------------------------------------------------------------
__global__ __launch_bounds__(512) void k_gru_attn_cvt(
    const float* __restrict__ xg, const float* __restrict__ h0,
    const float* __restrict__ w_hh, const float* __restrict__ b_hh,
    const float* __restrict__ hs, __hip_bfloat16* __restrict__ cat_bf,
    float* __restrict__ state_out, float* __restrict__ attw_out,
    const float* __restrict__ w_out, __hip_bfloat16* __restrict__ wout_bf) {
  if (blockIdx.x >= 32) {
    int idx = ((blockIdx.x - 32) * 512 + threadIdx.x) * 8;
    float4 a = *(const float4*)(w_out + idx);
    float4 c = *(const float4*)(w_out + idx + 4);
    union { __hip_bfloat16 h[8]; uint4 v; } p;
    p.h[0] = __float2bfloat16(a.x); p.h[1] = __float2bfloat16(a.y);
    p.h[2] = __float2bfloat16(a.z); p.h[3] = __float2bfloat16(a.w);
    p.h[4] = __float2bfloat16(c.x); p.h[5] = __float2bfloat16(c.y);
    p.h[6] = __float2bfloat16(c.z); p.h[7] = __float2bfloat16(c.w);
    *(uint4*)(wout_bf + idx) = p.v;
    return;
  }

  __shared__ __hip_bfloat16 ctb[128][128];  // GRU out (scan) -> P (phase 4)
  __shared__ __hip_bfloat16 hsb[128][128];  // hs rows,  chunk c ^ (e&7)
  __shared__ __hip_bfloat16 hsT[128][128];  // hs^T, col' = (e + 8*(h&15))&127
  __shared__ __align__(16) float hp[2][H_];

  const int b = blockIdx.x;
  const int t = threadIdx.x;
  const int hh = t >> 2;   // owned h element
  const int sub = t & 3;   // k-quarter

  float wr_[32], wz_[32], wn_[32];
#pragma unroll
  for (int m = 0; m < 8; m++) {
    int c = (m + sub * 2) & 7;
    int kb = sub * 32 + c * 4;
    *(float4*)&wr_[m * 4] = *(const float4*)(w_hh + (size_t)hh * H_ + kb);
    *(float4*)&wz_[m * 4] = *(const float4*)(w_hh + (size_t)(128 + hh) * H_ + kb);
    *(float4*)&wn_[m * 4] = *(const float4*)(w_hh + (size_t)(256 + hh) * H_ + kb);
  }

  const float* xgb = xg + (size_t)b * SDEC * G3;
  const float br = b_hh[hh], bz = b_hh[128 + hh], bn = b_hh[256 + hh];
  float cxr = xgb[hh], cxz = xgb[128 + hh], cxn = xgb[256 + hh];
  if (t < H_) hp[0][t] = h0[b * H_ + t];
  __hip_bfloat16* catbfb = cat_bf + (size_t)b * SDEC * 256;

  asm volatile("s_waitcnt lgkmcnt(0)" ::: "memory");
  __builtin_amdgcn_s_barrier();
  asm volatile("" ::: "memory");

  int cur = 0;
  for (int s = 0; s < SDEC; s++) {
    float nxr = 0.f, nxz = 0.f, nxn = 0.f;
    if (s + 1 < SDEC) {
      const float* xp = xgb + (size_t)(s + 1) * G3;
      nxr = xp[hh]; nxz = xp[128 + hh]; nxn = xp[256 + hh];
    }
    f32x2 sr2 = {0.f, 0.f}, sz2 = {0.f, 0.f}, sn2 = {0.f, 0.f};
#pragma unroll
    for (int m = 0; m < 8; m++) {
      int c = (m + sub * 2) & 7;
      float4 hv = *(const float4*)&hp[cur][sub * 32 + c * 4];
      f32x2 h01 = {hv.x, hv.y}, h23 = {hv.z, hv.w};
      const f32x2* w2r = (const f32x2*)&wr_[m * 4];
      const f32x2* w2z = (const f32x2*)&wz_[m * 4];
      const f32x2* w2n = (const f32x2*)&wn_[m * 4];
      sr2 += w2r[0] * h01; sr2 += w2r[1] * h23;
      sz2 += w2z[0] * h01; sz2 += w2z[1] * h23;
      sn2 += w2n[0] * h01; sn2 += w2n[1] * h23;
    }
    float sr = quad_reduce(sr2[0] + sr2[1]);
    float sz = quad_reduce(sz2[0] + sz2[1]);
    float sn = quad_reduce(sn2[0] + sn2[1]);

    float hold = hp[cur][hh];
    float r = fast_sigmoid(cxr + sr + br);
    float z = fast_sigmoid(cxz + sz + bz);
    float n = fast_tanh(cxn + r * (sn + bn));
    float hnew = (1.f - z) * n + z * hold;
    if (sub == 0) {
      __hip_bfloat16 hb = __float2bfloat16(hnew);
      hp[cur ^ 1][hh] = hnew;
      catbfb[(size_t)s * 256 + hh] = hb;
      ctb[s][((hh >> 3) ^ (s & 7)) * 8 + (hh & 7)] = hb;  // fragment layout
    }
    asm volatile("s_waitcnt lgkmcnt(0)" ::: "memory");
    __builtin_amdgcn_s_barrier();
    asm volatile("" ::: "memory");
    cur ^= 1;
    cxr = nxr; cxz = nxz; cxn = nxn;
  }

  // ================== fused attention (same block, batch b) ================
  const int w = t >> 6, l = t & 63;
  const int lr = l & 15, lk = l >> 4;
  const float* hsbase = hs + (size_t)b * SENC * H_;

  // stage hs (f32 -> bf16, swizzled rows) + final state
  for (int i = t; i < 2048; i += 512) {
    int e = i >> 4, c = i & 15;
    float4 v0 = *(const float4*)(hsbase + e * H_ + c * 8);
    float4 v1 = *(const float4*)(hsbase + e * H_ + c * 8 + 4);
    union { __hip_bfloat16 h[8]; uint4 u; } pk;
    pk.h[0] = __float2bfloat16(v0.x); pk.h[1] = __float2bfloat16(v0.y);
    pk.h[2] = __float2bfloat16(v0.z); pk.h[3] = __float2bfloat16(v0.w);
    pk.h[4] = __float2bfloat16(v1.x); pk.h[5] = __float2bfloat16(v1.y);
    pk.h[6] = __float2bfloat16(v1.z); pk.h[7] = __float2bfloat16(v1.w);
    *(uint4*)&hsb[e][((c ^ (e & 7)) * 8)] = pk.u;
  }
  if (t < H_) state_out[b * H_ + t] = hp[cur][t];
  __syncthreads();

  // build rotated hs^T from hsb
  for (int i = t; i < 2048; i += 512) {
    int c = i >> 7, e = i & 127;
    uint4 v = *(const uint4*)&hsb[e][((c ^ (e & 7)) * 8)];
    const __hip_bfloat16* hv = (const __hip_bfloat16*)&v;
#pragma unroll
    for (int u = 0; u < 8; u++) {
      int h = c * 8 + u;
      int col = (e + 8 * (h & 15)) & 127;
      hsT[h][col] = hv[u];
    }
  }
  // A-fragments (ct rows) into registers before ctb is overlaid by P
  const int d = w * 16 + lr;
  bf16x8 afrag[4];
#pragma unroll
  for (int kt = 0; kt < 4; kt++)
    afrag[kt] = *(const bf16x8*)&ctb[d][(((kt * 4 + lk) ^ (lr & 7)) * 8)];
  __syncthreads();  // hsT ready; all ctb reads complete

  // phase 2: scores S[d][e]
  f32x4 acc[8];
#pragma unroll
  for (int et = 0; et < 8; et++) acc[et] = (f32x4){0.f, 0.f, 0.f, 0.f};
#pragma unroll
  for (int et = 0; et < 8; et++) {
#pragma unroll
    for (int kt = 0; kt < 4; kt++) {
      bf16x8 bfrag =
          *(const bf16x8*)&hsb[et * 16 + lr][(((kt * 4 + lk) ^ (lr & 7)) * 8)];
      acc[et] =
          __builtin_amdgcn_mfma_f32_16x16x32_bf16(bfrag, afrag[kt], acc[et], 0, 0, 0);
    }
  }

  // phase 3: softmax over e, in-register
  float mx = -1e30f;
#pragma unroll
  for (int et = 0; et < 8; et++)
    mx = fmaxf(mx, fmaxf(fmaxf(acc[et][0], acc[et][1]),
                         fmaxf(acc[et][2], acc[et][3])));
  mx = fmaxf(mx, __shfl_xor(mx, 16));
  mx = fmaxf(mx, __shfl_xor(mx, 32));
  float sum = 0.f;
#pragma unroll
  for (int et = 0; et < 8; et++) {
    acc[et][0] = __expf(acc[et][0] - mx);
    acc[et][1] = __expf(acc[et][1] - mx);
    acc[et][2] = __expf(acc[et][2] - mx);
    acc[et][3] = __expf(acc[et][3] - mx);
    sum += acc[et][0] + acc[et][1] + acc[et][2] + acc[et][3];
  }
  sum += __shfl_xor(sum, 16);
  sum += __shfl_xor(sum, 32);
  const float inv = 1.f / sum;

  // write P (bf16, into ctb space) + attw (f32)
  __hip_bfloat16 (*plds)[128] = ctb;
  float* aw = attw_out + (size_t)b * SENC * SDEC + d;
#pragma unroll
  for (int et = 0; et < 8; et++) {
    acc[et][0] *= inv; acc[et][1] *= inv;
    acc[et][2] *= inv; acc[et][3] *= inv;
    union { __hip_bfloat16 h[4]; uint2 u; } pk4;
    pk4.h[0] = __float2bfloat16(acc[et][0]);
    pk4.h[1] = __float2bfloat16(acc[et][1]);
    pk4.h[2] = __float2bfloat16(acc[et][2]);
    pk4.h[3] = __float2bfloat16(acc[et][3]);
    *(uint2*)&plds[d][(((et * 2 + (lk >> 1)) ^ (lr & 7)) * 8 + 4 * (lk & 1))] =
        pk4.u;
    const int e0 = et * 16 + lk * 4;
#pragma unroll
    for (int j = 0; j < 4; j++)
      aw[(size_t)(e0 + j) * SDEC] = acc[et][j];
  }
  __syncthreads();

  // phase 4: context c[d][h] = P @ hs
  bf16x8 pfrag[4];
#pragma unroll
  for (int f = 0; f < 4; f++)
    pfrag[f] = *(const bf16x8*)&plds[d][(((f * 4 + lk) ^ (lr & 7)) * 8)];
#pragma unroll
  for (int ht = 0; ht < 8; ht++) {
    f32x4 a2 = (f32x4){0.f, 0.f, 0.f, 0.f};
#pragma unroll
    for (int kt = 0; kt < 4; kt++) {
      bf16x8 hfrag =
          *(const bf16x8*)&hsT[ht * 16 + lr][((kt * 32 + lk * 8 + 8 * lr) & 127)];
      a2 = __builtin_amdgcn_mfma_f32_16x16x32_bf16(hfrag, pfrag[kt], a2, 0, 0, 0);
    }
    union { __hip_bfloat16 h[4]; uint2 u; } pk4;
    pk4.h[0] = __float2bfloat16(a2[0]);
    pk4.h[1] = __float2bfloat16(a2[1]);
    pk4.h[2] = __float2bfloat16(a2[2]);
    pk4.h[3] = __float2bfloat16(a2[3]);
    *(uint2*)(cat_bf + (size_t)(b * SDEC + d) * 256 + 128 + ht * 16 + lk * 4) =
        pk4.u;
  }
}

// ---------------------------------------------------------------------------
// Kernel 4: logits = cat @ w_out^T + b_out   (unchanged — near write-BW floor)
// ---------------------------------------------------------------------------
__global__ __launch_bounds__(512) void k_gemm_mfma(
    const __hip_bfloat16* __restrict__ A, const __hip_bfloat16* __restrict__ Bw,
    const float* __restrict__ b_out, float* __restrict__ C) {
  constexpr int K = 256, N = V_, Kt = 32;
  alignas(16) __shared__ char smem[73728];  // 72 KB
  __hip_bfloat16 (*As)[4096] = (__hip_bfloat16(*)[4096])smem;            // [3][128*32]
  __hip_bfloat16 (*Bs)[8192] = (__hip_bfloat16(*)[8192])(smem + 24576);  // [3][256*32]
  float* tr = (float*)smem;  // epilogue: [64][260] padded f32 half-tile

  const int tid = threadIdx.x;
  const int w = tid >> 6, l = tid & 63;
  const int wr = w >> 2, wc = w & 3;       // 2M x 4N waves, each 64x64
  const int lr = l & 15, lk = l >> 4;
  const int lq = l >> 2, lc = l & 3;

  const int bid = blockIdx.x;
  const int wgid = (bid & 7) * 500 + (bid >> 3);
  const int mt = wgid & 31;
  const int nt = wgid >> 5;
  const int m0 = mt * 128, n0 = nt * 256;

  f32x4 acc[4][4];
#pragma unroll
  for (int m = 0; m < 4; m++)
#pragma unroll
    for (int n = 0; n < 4; n++) acc[m][n] = (f32x4){0.f, 0.f, 0.f, 0.f};

#define STAGE(buf, kk)                                                            \
  do {                                                                            \
    const __hip_bfloat16* gA = A + (size_t)(m0 + w * 16 + lq) * K + (kk) + lc * 8;\
    const __hip_bfloat16* gB0 = Bw + (size_t)(n0 + w * 32 + lq) * K + (kk) + lc * 8;\
    const __hip_bfloat16* gB1 = gB0 + (size_t)16 * K;                             \
    __builtin_amdgcn_global_load_lds((const GLOBAL_AS void*)gA,                   \
        (LDS_AS void*)(&As[buf][w * 512]), 16, 0, 0);                             \
    __builtin_amdgcn_global_load_lds((const GLOBAL_AS void*)gB0,                  \
        (LDS_AS void*)(&Bs[buf][w * 1024]), 16, 0, 0);                            \
    __builtin_amdgcn_global_load_lds((const GLOBAL_AS void*)gB1,                  \
        (LDS_AS void*)(&Bs[buf][w * 1024 + 512]), 16, 0, 0);                      \
  } while (0)

  STAGE(0, 0);
  STAGE(1, Kt);

#pragma unroll
  for (int t = 0; t < 8; ++t) {
    if (t < 7) asm volatile("s_waitcnt vmcnt(3)" ::: "memory");
    else       asm volatile("s_waitcnt vmcnt(0)" ::: "memory");
    __builtin_amdgcn_s_barrier();
    asm volatile("" ::: "memory");

    const int c = t % 3;
    bf16x8 af[4], bfr[4];
#pragma unroll
    for (int m = 0; m < 4; m++)
      af[m] = *(const bf16x8*)(const void*)(&As[c][(wr * 64 + m * 16 + lr) * Kt + lk * 8]);
#pragma unroll
    for (int n = 0; n < 4; n++)
      bfr[n] = *(const bf16x8*)(const void*)(&Bs[c][(wc * 64 + n * 16 + lr) * Kt + lk * 8]);

    if (t < 6) STAGE((t + 2) % 3, (t + 2) * Kt);

#pragma unroll
    for (int m = 0; m < 4; m++)
#pragma unroll
      for (int n = 0; n < 4; n++)
        acc[m][n] = __builtin_amdgcn_mfma_f32_16x16x32_bf16(bfr[n], af[m], acc[m][n], 0, 0, 0);
  }
#undef STAGE

  __syncthreads();
#pragma unroll
  for (int h = 0; h < 2; ++h) {
    if (wr == h) {
#pragma unroll
      for (int m = 0; m < 4; m++) {
#pragma unroll
        for (int n = 0; n < 4; n++) {
          const int row = m * 16 + lr;
          const int col = wc * 64 + n * 16 + lk * 4;
          const float4 bo = *(const float4*)(b_out + n0 + col);
          f32x4 v;
          v[0] = acc[m][n][0] + bo.x;
          v[1] = acc[m][n][1] + bo.y;
          v[2] = acc[m][n][2] + bo.z;
          v[3] = acc[m][n][3] + bo.w;
          *(f32x4*)&tr[row * 260 + col] = v;
        }
      }
    }
    __syncthreads();
#pragma unroll
    for (int i = 0; i < 8; ++i) {
      const int c2 = i * 512 + tid;
      const int row = c2 >> 6;
      const int off = (c2 & 63) * 4;
      f32x4 v = *(const f32x4*)&tr[row * 260 + off];
      __builtin_nontemporal_store(
          v, (f32x4*)(C + (size_t)(m0 + h * 64 + row) * N + n0 + off));
    }
    __syncthreads();
  }
}

// ---------------------------------------------------------------------------
extern "C" void kernel_launch(void* const* d_in, const int* in_sizes, int n_in,
                              void* d_out, int out_size, void* d_ws, size_t ws_size,
                              hipStream_t stream) {
  const int* seq = (const int*)d_in[0];
  const float* hs = (const float*)d_in[1];
  const float* h0 = (const float*)d_in[2];
  const float* emb = (const float*)d_in[3];
  const float* w_ih = (const float*)d_in[4];
  const float* w_hh = (const float*)d_in[5];
  const float* b_ih = (const float*)d_in[6];
  const float* b_hh = (const float*)d_in[7];
  const float* w_out = (const float*)d_in[8];
  const float* b_out = (const float*)d_in[9];

  float* out = (float*)d_out;
  float* logits = out;                          // 131,072,000 f32
  float* state = out + 131072000;               // 4,096 f32
  float* attw = out + 131072000 + 4096;         // 524,288 f32

  char* ws = (char*)d_ws;
  float* xg = (float*)ws;                              // 6,291,456 B
  __hip_bfloat16* cat_bf = (__hip_bfloat16*)(ws + 10485760);   // 2,097,152 B
  __hip_bfloat16* wout_bf = (__hip_bfloat16*)(ws + 12582912);  // 16,384,000 B

  k_embed_proj<<<256, 192, 0, stream>>>(seq, emb, w_ih, b_ih, xg);
  k_gru_attn_cvt<<<2032, 512, 0, stream>>>(xg, h0, w_hh, b_hh, hs, cat_bf,
                                           state, attw, w_out, wout_bf);
  k_gemm_mfma<<<4000, 512, 0, stream>>>(cat_bf, wout_bf, b_out, logits);
}